// Round 1
// baseline (583.793 us; speedup 1.0000x reference)
//
#include <hip/hip_runtime.h>
#include <math.h>

#define D_MODEL 4096
#define N_EXP   64
#define N_ROWS  16384          // 4 * 4096
#define LN_EPS  1e-5f
#define TM      64             // rows per block
#define KC      64             // k-chunk
#define LDP     (TM + 4)       // padded LDS leading dim (68): 2-way bank alias = free
#define NBLK    (N_ROWS / TM)  // 256 blocks

// ------------------------------------------------------------------
// ws layout (floats):
//   [0, 262144)        gW[e][d] = W[e][d] * gamma[d]
//   [262144, 262208)   G[e] = sum_d gamma[d]*W[e][d]
//   [262208, 262272)   C[e] = sum_d beta[d]*W[e][d] + b[e]
//   [262272, 278656)   partials[NBLK][64] per-block mean_w sums
// ------------------------------------------------------------------

__global__ __launch_bounds__(256) void prep_kernel(
    const float* __restrict__ W, const float* __restrict__ gamma,
    const float* __restrict__ beta, const float* __restrict__ bias,
    float* __restrict__ gW, float* __restrict__ G, float* __restrict__ C)
{
  int e = blockIdx.x, t = threadIdx.x;
  const float* w = W + (size_t)e * D_MODEL;
  float* gw = gW + (size_t)e * D_MODEL;
  float sg = 0.f, sb = 0.f;
  for (int d = t; d < D_MODEL; d += 256) {
    float wv = w[d], gv = gamma[d], bv = beta[d];
    float p = wv * gv;
    gw[d] = p;
    sg += p;
    sb += wv * bv;
  }
#pragma unroll
  for (int o = 32; o > 0; o >>= 1) {
    sg += __shfl_xor(sg, o, 64);
    sb += __shfl_xor(sb, o, 64);
  }
  __shared__ float rg_[4], rb_[4];
  int wid = t >> 6, ln = t & 63;
  if (ln == 0) { rg_[wid] = sg; rb_[wid] = sb; }
  __syncthreads();
  if (t == 0) {
    G[e] = rg_[0] + rg_[1] + rg_[2] + rg_[3];
    C[e] = rb_[0] + rb_[1] + rb_[2] + rb_[3] + bias[e];
  }
}

__global__ __launch_bounds__(256) void router_main(
    const float* __restrict__ x, const float* __restrict__ gW,
    const float* __restrict__ G, const float* __restrict__ C,
    float* __restrict__ out_sw, float* __restrict__ out_idx,
    float* __restrict__ out_partials, int k)
{
  __shared__ float xt[KC * LDP];   // x tile, k-major: xt[k][row]
  __shared__ float wt[KC * LDP];   // gW tile, k-major: wt[k][expert]

  const int t   = threadIdx.x;
  const int blk = blockIdx.x;
  const size_t row_base = (size_t)blk * TM;

  // staging mapping: thread t loads row/expert (t>>2), 4 float4s
  const int srow = t >> 2;
  const int sk0  = (t & 3) * 4;
  const float* xrow = x  + (row_base + srow) * D_MODEL;
  const float* wrow = gW + (size_t)srow * D_MODEL;

  // compute mapping: 4x4 tile per thread
  const int rg = t >> 4;   // row group   (rows 4*rg .. +3)
  const int eg = t & 15;   // expert group(exp  4*eg .. +3)

  float acc[4][4] = {{0.f}};
  float Sp = 0.f, Qp = 0.f;

  for (int c = 0; c < D_MODEL / KC; ++c) {
    const int kb = c * KC;
    float4 xv[4], wv[4];
#pragma unroll
    for (int i = 0; i < 4; ++i) {
      xv[i] = *(const float4*)(xrow + kb + sk0 + i * 16);
      wv[i] = *(const float4*)(wrow + kb + sk0 + i * 16);
    }
    __syncthreads();   // previous chunk's GEMM reads done before overwrite
#pragma unroll
    for (int i = 0; i < 4; ++i) {
      const int k0 = sk0 + i * 16;
      xt[(k0 + 0) * LDP + srow] = xv[i].x;
      xt[(k0 + 1) * LDP + srow] = xv[i].y;
      xt[(k0 + 2) * LDP + srow] = xv[i].z;
      xt[(k0 + 3) * LDP + srow] = xv[i].w;
      wt[(k0 + 0) * LDP + srow] = wv[i].x;
      wt[(k0 + 1) * LDP + srow] = wv[i].y;
      wt[(k0 + 2) * LDP + srow] = wv[i].z;
      wt[(k0 + 3) * LDP + srow] = wv[i].w;
      Sp += xv[i].x + xv[i].y + xv[i].z + xv[i].w;
      Qp = fmaf(xv[i].x, xv[i].x, Qp);
      Qp = fmaf(xv[i].y, xv[i].y, Qp);
      Qp = fmaf(xv[i].z, xv[i].z, Qp);
      Qp = fmaf(xv[i].w, xv[i].w, Qp);
    }
    __syncthreads();
#pragma unroll 16
    for (int k = 0; k < KC; ++k) {
      const float4 a  = *(const float4*)(xt + k * LDP + 4 * rg);
      const float4 bv = *(const float4*)(wt + k * LDP + 4 * eg);
      acc[0][0] = fmaf(a.x, bv.x, acc[0][0]);
      acc[0][1] = fmaf(a.x, bv.y, acc[0][1]);
      acc[0][2] = fmaf(a.x, bv.z, acc[0][2]);
      acc[0][3] = fmaf(a.x, bv.w, acc[0][3]);
      acc[1][0] = fmaf(a.y, bv.x, acc[1][0]);
      acc[1][1] = fmaf(a.y, bv.y, acc[1][1]);
      acc[1][2] = fmaf(a.y, bv.z, acc[1][2]);
      acc[1][3] = fmaf(a.y, bv.w, acc[1][3]);
      acc[2][0] = fmaf(a.z, bv.x, acc[2][0]);
      acc[2][1] = fmaf(a.z, bv.y, acc[2][1]);
      acc[2][2] = fmaf(a.z, bv.z, acc[2][2]);
      acc[2][3] = fmaf(a.z, bv.w, acc[2][3]);
      acc[3][0] = fmaf(a.w, bv.x, acc[3][0]);
      acc[3][1] = fmaf(a.w, bv.y, acc[3][1]);
      acc[3][2] = fmaf(a.w, bv.z, acc[3][2]);
      acc[3][3] = fmaf(a.w, bv.w, acc[3][3]);
    }
  }

  // ---- LN stats: reduce Sp/Qp (4 staging threads per row) ----
  __syncthreads();
  xt[t]       = Sp;
  xt[256 + t] = Qp;
  __shared__ float mu_s[TM], rs_s[TM];
  __syncthreads();
  if (t < TM) {
    float S = xt[t * 4] + xt[t * 4 + 1] + xt[t * 4 + 2] + xt[t * 4 + 3];
    float Q = xt[256 + t * 4] + xt[256 + t * 4 + 1] + xt[256 + t * 4 + 2] + xt[256 + t * 4 + 3];
    float mu  = S * (1.f / D_MODEL);
    float var = Q * (1.f / D_MODEL) - mu * mu;
    mu_s[t] = mu;
    rs_s[t] = rsqrtf(var + LN_EPS);
  }
  __syncthreads();

  // ---- logits into LDS (reuse wt): logit = rstd*(acc - mu*G[e]) + C[e] ----
  float Gv[4], Cv[4];
#pragma unroll
  for (int j = 0; j < 4; ++j) { Gv[j] = G[4 * eg + j]; Cv[j] = C[4 * eg + j]; }
  float* lg = wt;
#pragma unroll
  for (int i = 0; i < 4; ++i) {
    const int r = 4 * rg + i;
    const float mu = mu_s[r], rs = rs_s[r];
#pragma unroll
    for (int j = 0; j < 4; ++j) {
      lg[r * LDP + 4 * eg + j] = rs * (acc[i][j] - mu * Gv[j]) + Cv[j];
    }
  }
  __syncthreads();

  // ---- epilogue: wave per row (16 rows per wave), lane = expert ----
  const int wid  = t >> 6;
  const int lane = t & 63;
  float mw = 0.f;
  for (int rr = 0; rr < 16; ++rr) {
    const int r = wid * 16 + rr;
    const float l = lg[r * LDP + lane];
    float m = l;
#pragma unroll
    for (int o = 32; o > 0; o >>= 1) m = fmaxf(m, __shfl_xor(m, o, 64));
    const float p = __expf(l - m);
    float s = p;
#pragma unroll
    for (int o = 32; o > 0; o >>= 1) s += __shfl_xor(s, o, 64);
    const float w = p / s;
    mw += w;

    float rem = w;       // masked copy for iterative top-k
    float denom = 0.f;
    float myval = 0.f;
    for (int j = 0; j < k; ++j) {
      float mx = rem;
#pragma unroll
      for (int o = 32; o > 0; o >>= 1) mx = fmaxf(mx, __shfl_xor(mx, o, 64));
      const unsigned long long ball = __ballot(rem == mx);
      const int ie = __ffsll((long long)ball) - 1;   // lowest index on ties (jax semantics)
      denom += mx;
      if (lane == ie) { myval = w; rem = -1.f; }
      if (lane == j) out_idx[(row_base + r) * k + j] = (float)ie;
    }
    denom += 1e-8f;
    out_sw[(row_base + r) * N_EXP + lane] = myval / denom;
  }

  // ---- per-block mean_w partial (deterministic, no atomics) ----
  __syncthreads();
  xt[wid * 64 + lane] = mw;
  __syncthreads();
  if (t < 64)
    out_partials[blk * 64 + t] = xt[t] + xt[64 + t] + xt[128 + t] + xt[192 + t];
}

__global__ void loss_kernel(const float* __restrict__ partials, float* __restrict__ out_loss)
{
  const int e = threadIdx.x;  // 64 threads
  float s = 0.f;
  for (int b = 0; b < NBLK; ++b) s += partials[b * 64 + e];
  const float m = s * (1.f / N_ROWS);
  float v = -m * logf(m + 1e-8f);
#pragma unroll
  for (int o = 32; o > 0; o >>= 1) v += __shfl_xor(v, o, 64);
  if (e == 0) out_loss[0] = v;
}

extern "C" void kernel_launch(void* const* d_in, const int* in_sizes, int n_in,
                              void* d_out, int out_size, void* d_ws, size_t ws_size,
                              hipStream_t stream)
{
  const float* x     = (const float*)d_in[0];
  const float* gamma = (const float*)d_in[1];
  const float* beta  = (const float*)d_in[2];
  const float* W     = (const float*)d_in[3];
  const float* bias  = (const float*)d_in[4];

  float* ws       = (float*)d_ws;
  float* gW       = ws;
  float* G        = ws + 262144;
  float* C        = ws + 262208;
  float* partials = ws + 262272;

  // k from output layout: out_size = N_ROWS*N_EXP + N_ROWS*k + 1
  int k = (out_size - N_ROWS * N_EXP - 1) / N_ROWS;
  if (k < 1) k = 1;
  if (k > 8) k = 8;

  float* out      = (float*)d_out;
  float* out_sw   = out;
  float* out_idx  = out + (size_t)N_ROWS * N_EXP;
  float* out_loss = out + (size_t)N_ROWS * N_EXP + (size_t)N_ROWS * k;

  hipLaunchKernelGGL(prep_kernel, dim3(N_EXP), dim3(256), 0, stream,
                     W, gamma, beta, bias, gW, G, C);
  hipLaunchKernelGGL(router_main, dim3(NBLK), dim3(256), 0, stream,
                     x, gW, G, C, out_sw, out_idx, partials, k);
  hipLaunchKernelGGL(loss_kernel, dim3(1), dim3(64), 0, stream,
                     partials, out_loss);
}